// Round 2
// baseline (647.292 us; speedup 1.0000x reference)
//
#include <hip/hip_runtime.h>
#include <hip/hip_cooperative_groups.h>
#include <math.h>

namespace cg = cooperative_groups;

static constexpr int BROWS   = 16384;
static constexpr int NC      = 784;
static constexpr int THREADS = 512;
static constexpr int NSLOT   = 2;               // ceil(784/512)
static constexpr int NREP    = 4;               // replicated stat accumulators
static constexpr float EPS   = 1e-5f;
static constexpr float INV_B = 1.0f / (float)BROWS;

// fused persistent-kernel geometry: 1024 blocks x 512 thr, 16 rows/block.
// LDS = 4 quads * 784 * 8B + 2*784*4B = 31360 B -> 4 blocks/CU (32 waves/CU,
// VGPR<=64 via launch_bounds(512,8)); cooperative grid 1024 = 256 CU * 4.
static constexpr int TRB  = 16;
static constexpr int NQ   = TRB / 4;            // 4 row-quads
static constexpr int NBLK = BROWS / TRB;        // 1024

#if defined(__has_builtin)
#if __has_builtin(__builtin_amdgcn_global_load_lds)
#define HAVE_ASYNC_LDS 1
#endif
#if __has_builtin(__builtin_amdgcn_rcpf)
#define HAVE_RCPF 1
#endif
#if __has_builtin(__builtin_elementwise_fma)
#define HAVE_EW_FMA 1
#endif
#endif

typedef float v2f __attribute__((ext_vector_type(2)));

__device__ __forceinline__ void stage16(const float4* g, float4* l) {
#ifdef HAVE_ASYNC_LDS
    __builtin_amdgcn_global_load_lds(
        (const __attribute__((address_space(1))) void*)g,
        (__attribute__((address_space(3))) void*)l, 16, 0, 0);
#else
    *l = *g;
#endif
}

// ---- bf16 helpers (raw u16 storage; RNE convert) ----
__device__ __forceinline__ unsigned short f2b(float f) {
    union { float f; unsigned u; } v; v.f = f;
    const unsigned r = v.u + 0x7fffu + ((v.u >> 16) & 1u);
    return (unsigned short)(r >> 16);
}
__device__ __forceinline__ unsigned pack2(float lo, float hi) {
    return (unsigned)f2b(lo) | ((unsigned)f2b(hi) << 16);
}
__device__ __forceinline__ unsigned long long pack4(float a, float b, float c, float d) {
    return (unsigned long long)pack2(a, b) | ((unsigned long long)pack2(c, d) << 32);
}
__device__ __forceinline__ float fast_rcp(float x) {
#ifdef HAVE_RCPF
    return __builtin_amdgcn_rcpf(x);
#else
    return 1.0f / x;
#endif
}

// tanh-form gelu (max |err| ~3e-4), branchless, correct limits.
__device__ __forceinline__ float gelu_f(float x) {
    const float u  = x * x;
    const float z  = x * fmaf(0.0356774081f, u, 0.7978845608f);
    const float e  = __expf(2.0f * z);
    const float r  = fast_rcp(e + 1.0f);
    const float t  = fmaf(-2.0f, r, 1.0f);
    const float hx = 0.5f * x;
    return fmaf(hx, t, hx);
}

// u64 = 4 bf16 rows of one column. Unpack to 2x v2f and packed-FMA.
__device__ __forceinline__ void fmaq(const unsigned long long v, const float w, v2f acc[2]) {
    const unsigned lo = (unsigned)v, hi = (unsigned)(v >> 32);
    union { unsigned u; float f; } a0, a1, b0, b1;
    a0.u = lo << 16; a1.u = lo & 0xffff0000u;
    b0.u = hi << 16; b1.u = hi & 0xffff0000u;
    const v2f a = { a0.f, a1.f }, b = { b0.f, b1.f };
    const v2f w2 = { w, w };
#ifdef HAVE_EW_FMA
    acc[0] = __builtin_elementwise_fma(a, w2, acc[0]);
    acc[1] = __builtin_elementwise_fma(b, w2, acc[1]);
#else
    acc[0] += a * w2;
    acc[1] += b * w2;
#endif
}

// ================= fused persistent kernel =================

// One sparse layer (+gelu, optional BN-fold, optional stats) over NQ row-quads
// for one column j. Outputs to registers o[NQ]; tile is only READ here
// (barrier + write-back handles the in-place WAR hazard).
template<int K, bool FOLD, bool STATS>
__device__ __forceinline__ void sparse_quads(
    const unsigned long long* __restrict__ tile,
    const float* __restrict__ s_sc, const float* __restrict__ s_sh,
    const int* __restrict__ idx, const float* __restrict__ W,
    const float* __restrict__ bias, const int j,
    unsigned long long o[NQ], float& s1, float& s2)
{
    int ji[K]; float jw[K];
    float jb = bias[j];
    #pragma unroll
    for (int k = 0; k < K; ++k) {
        const int   c = idx[K * j + k];
        const float w = W[K * j + k];
        ji[k] = c;
        if (FOLD) { jw[k] = w * s_sc[c]; jb = fmaf(w, s_sh[c], jb); }
        else      { jw[k] = w; }
    }
    #pragma unroll
    for (int q = 0; q < NQ; ++q) {
        v2f a0[2] = { { jb, jb }, { jb, jb } };
        v2f a1[2] = { { 0.f, 0.f }, { 0.f, 0.f } };
        #pragma unroll
        for (int k = 0; k < K; ++k)
            fmaq(tile[q * NC + ji[k]], jw[k], (k & 1) ? a1 : a0);
        const v2f r0v = a0[0] + a1[0], r1v = a0[1] + a1[1];
        const float u0 = gelu_f(r0v.x), u1 = gelu_f(r0v.y);
        const float u2 = gelu_f(r1v.x), u3 = gelu_f(r1v.y);
        if (STATS) {
            s1 += (u0 + u1) + (u2 + u3);
            s2 = fmaf(u0, u0, fmaf(u1, u1, fmaf(u2, u2, fmaf(u3, u3, s2))));
        }
        o[q] = pack4(u0, u1, u2, u3);
    }
}

__device__ __forceinline__ void writeback(unsigned long long* __restrict__ tile,
                                          const int tid, const int j1,
                                          const unsigned long long o0[NQ],
                                          const unsigned long long o1[NQ])
{
    #pragma unroll
    for (int q = 0; q < NQ; ++q) tile[q * NC + tid] = o0[q];
    if (j1 < NC) {
        #pragma unroll
        for (int q = 0; q < NQ; ++q) tile[q * NC + j1] = o1[q];
    }
}

__device__ __forceinline__ void finalize_bn(const float* __restrict__ psum,
                                            const float* __restrict__ psq,
                                            const float* __restrict__ gamma,
                                            const float* __restrict__ beta,
                                            float* __restrict__ s_sc,
                                            float* __restrict__ s_sh, const int tid)
{
    #pragma unroll
    for (int s = 0; s < NSLOT; ++s) {
        const int j = tid + s * THREADS;
        if (j < NC) {
            float s1 = 0.f, s2 = 0.f;
            #pragma unroll
            for (int r = 0; r < NREP; ++r) { s1 += psum[r * NC + j]; s2 += psq[r * NC + j]; }
            const float m   = s1 * INV_B;
            const float var = fmaf(-m, m, s2 * INV_B);
            const float sc  = gamma[j] * rsqrtf(var + EPS);
            s_sc[j] = sc;
            s_sh[j] = fmaf(-m, sc, beta[j]);
        }
    }
}

__global__ __launch_bounds__(THREADS, 8)
void fused(const float* __restrict__ x,
           const int* __restrict__ idx1, const float* __restrict__ W1, const float* __restrict__ b1,
           const int* __restrict__ idx2, const float* __restrict__ W2, const float* __restrict__ b2,
           const int* __restrict__ idx3, const float* __restrict__ W3, const float* __restrict__ b3,
           const float* __restrict__ g2, const float* __restrict__ be2,
           const float* __restrict__ g3, const float* __restrict__ be3,
           float* __restrict__ out,
           float* __restrict__ sum2a, float* __restrict__ ssq2a,
           float* __restrict__ sum3,  float* __restrict__ ssq3,
           float* __restrict__ sum2b, float* __restrict__ ssq2b)
{
    __shared__ unsigned long long tile[NQ * NC];   // 25088 B, bf16 quad-packed
    __shared__ float s_sc[NC], s_sh[NC];           //  6272 B
    cg::grid_group grid = cg::this_grid();

    const int tid  = threadIdx.x;
    const int row0 = blockIdx.x * TRB;
    const int rep  = blockIdx.x & (NREP - 1);
    const int j1   = tid + THREADS;                // second column slot

    // ---- stage x -> bf16 quad tile (coalesced row reads) ----
    #pragma unroll
    for (int s = 0; s < NSLOT; ++s) {
        const int c = tid + s * THREADS;
        if (c < NC) {
            #pragma unroll
            for (int q = 0; q < NQ; ++q) {
                const size_t base = (size_t)(row0 + 4 * q) * NC + c;
                tile[q * NC + c] = pack4(x[base], x[base + NC], x[base + 2 * NC], x[base + 3 * NC]);
            }
        }
    }
    __syncthreads();

    unsigned long long o0[NQ], o1[NQ];
    float s1a, s2a, s1b, s2b;

    // ---- L1: sp1 -> gelu ----
    sparse_quads<2, false, false>(tile, s_sc, s_sh, idx1, W1, b1, tid, o0, s1a, s2a);
    if (j1 < NC)
        sparse_quads<2, false, false>(tile, s_sc, s_sh, idx1, W1, b1, j1, o1, s1b, s2b);
    __syncthreads();                       // all reads of tile done
    writeback(tile, tid, j1, o0, o1);
    __syncthreads();

    // ---- L2a: sp2 -> gelu (+bn2a stats) ----
    s1a = s2a = s1b = s2b = 0.f;
    sparse_quads<4, false, true>(tile, s_sc, s_sh, idx2, W2, b2, tid, o0, s1a, s2a);
    if (j1 < NC)
        sparse_quads<4, false, true>(tile, s_sc, s_sh, idx2, W2, b2, j1, o1, s1b, s2b);
    __syncthreads();
    writeback(tile, tid, j1, o0, o1);
    atomicAdd(&sum2a[rep * NC + tid], s1a); atomicAdd(&ssq2a[rep * NC + tid], s2a);
    if (j1 < NC) { atomicAdd(&sum2a[rep * NC + j1], s1b); atomicAdd(&ssq2a[rep * NC + j1], s2b); }
    grid.sync();                           // partials visible; also orders writeback
    finalize_bn(sum2a, ssq2a, g2, be2, s_sc, s_sh, tid);
    __syncthreads();

    // ---- L3: fold bn2a -> sp3 -> gelu (+bn3 stats) ----
    s1a = s2a = s1b = s2b = 0.f;
    sparse_quads<8, true, true>(tile, s_sc, s_sh, idx3, W3, b3, tid, o0, s1a, s2a);
    if (j1 < NC)
        sparse_quads<8, true, true>(tile, s_sc, s_sh, idx3, W3, b3, j1, o1, s1b, s2b);
    __syncthreads();
    writeback(tile, tid, j1, o0, o1);
    atomicAdd(&sum3[rep * NC + tid], s1a); atomicAdd(&ssq3[rep * NC + tid], s2a);
    if (j1 < NC) { atomicAdd(&sum3[rep * NC + j1], s1b); atomicAdd(&ssq3[rep * NC + j1], s2b); }
    grid.sync();
    finalize_bn(sum3, ssq3, g3, be3, s_sc, s_sh, tid);
    __syncthreads();

    // ---- L2b: fold bn3 -> sp2 -> gelu (+bn2b stats) ----
    s1a = s2a = s1b = s2b = 0.f;
    sparse_quads<4, true, true>(tile, s_sc, s_sh, idx2, W2, b2, tid, o0, s1a, s2a);
    if (j1 < NC)
        sparse_quads<4, true, true>(tile, s_sc, s_sh, idx2, W2, b2, j1, o1, s1b, s2b);
    __syncthreads();
    writeback(tile, tid, j1, o0, o1);
    atomicAdd(&sum2b[rep * NC + tid], s1a); atomicAdd(&ssq2b[rep * NC + tid], s2a);
    if (j1 < NC) { atomicAdd(&sum2b[rep * NC + j1], s1b); atomicAdd(&ssq2b[rep * NC + j1], s2b); }
    grid.sync();
    finalize_bn(sum2b, ssq2b, g2, be2, s_sc, s_sh, tid);
    __syncthreads();

    // ---- L1b: fold bn2b -> sp1 -> relu -> out (fp32, coalesced) ----
    #pragma unroll
    for (int s = 0; s < NSLOT; ++s) {
        const int j = tid + s * THREADS;
        if (j < NC) {
            int ji[2]; float jw[2];
            float jb = b1[j];
            #pragma unroll
            for (int k = 0; k < 2; ++k) {
                const int   c = idx1[2 * j + k];
                const float w = W1[2 * j + k];
                ji[k] = c; jw[k] = w * s_sc[c]; jb = fmaf(w, s_sh[c], jb);
            }
            #pragma unroll
            for (int q = 0; q < NQ; ++q) {
                v2f a0[2] = { { jb, jb }, { jb, jb } };
                v2f a1[2] = { { 0.f, 0.f }, { 0.f, 0.f } };
                fmaq(tile[q * NC + ji[0]], jw[0], a0);
                fmaq(tile[q * NC + ji[1]], jw[1], a1);
                const v2f r0v = a0[0] + a1[0], r1v = a0[1] + a1[1];
                const size_t base = (size_t)(row0 + 4 * q) * NC + j;
                out[base         ] = fmaxf(r0v.x, 0.f);
                out[base +     NC] = fmaxf(r0v.y, 0.f);
                out[base + 2 * NC] = fmaxf(r1v.x, 0.f);
                out[base + 3 * NC] = fmaxf(r1v.y, 0.f);
            }
        }
    }
}

// ================= fallback: original 4-kernel pipeline =================

__global__ __launch_bounds__(THREADS, 6)
void k12(const float* __restrict__ x,
         const int* __restrict__ idx1, const float* __restrict__ W1, const float* __restrict__ b1,
         const int* __restrict__ idx2, const float* __restrict__ W2, const float* __restrict__ b2,
         unsigned long long* __restrict__ outr,
         float* __restrict__ ssum, float* __restrict__ ssq)
{
    __shared__ unsigned long long tileX[4 * NC];
    __shared__ unsigned long long tileH[4 * NC];
    const int tid  = threadIdx.x;
    const int row0 = blockIdx.x * TRB;

    #pragma unroll
    for (int slot = 0; slot < NSLOT; ++slot) {
        const int c = tid + slot * THREADS;
        if (c < NC) {
            #pragma unroll
            for (int q = 0; q < 4; ++q) {
                const size_t base = (size_t)(row0 + 4 * q) * NC + c;
                tileX[q * NC + c] = pack4(x[base], x[base + NC], x[base + 2 * NC], x[base + 3 * NC]);
            }
        }
    }
    __syncthreads();

    #pragma unroll
    for (int slot = 0; slot < NSLOT; ++slot) {
        const int j = tid + slot * THREADS;
        if (j < NC) {
            const int   c0 = idx1[2 * j], c1 = idx1[2 * j + 1];
            const float w0 = W1[2 * j],   w1 = W1[2 * j + 1], bb = b1[j];
            #pragma unroll
            for (int q = 0; q < 4; ++q) {
                v2f acc[2] = { { bb, bb }, { bb, bb } };
                fmaq(tileX[q * NC + c0], w0, acc);
                fmaq(tileX[q * NC + c1], w1, acc);
                tileH[q * NC + j] = pack4(gelu_f(acc[0].x), gelu_f(acc[0].y),
                                          gelu_f(acc[1].x), gelu_f(acc[1].y));
            }
        }
    }
    __syncthreads();

    const int rep = blockIdx.x & (NREP - 1);
    unsigned long long* dst = outr + (size_t)blockIdx.x * 4 * NC;
    #pragma unroll
    for (int slot = 0; slot < NSLOT; ++slot) {
        const int j = tid + slot * THREADS;
        if (j < NC) {
            int ji[4]; float jw[4];
            #pragma unroll
            for (int k = 0; k < 4; ++k) { ji[k] = idx2[4 * j + k]; jw[k] = W2[4 * j + k]; }
            const float jb = b2[j];
            float s1 = 0.0f, s2 = 0.0f;
            #pragma unroll
            for (int q = 0; q < 4; ++q) {
                v2f acc[2] = { { jb, jb }, { jb, jb } };
                #pragma unroll
                for (int k = 0; k < 4; ++k) fmaq(tileH[q * NC + ji[k]], jw[k], acc);
                const float u0 = gelu_f(acc[0].x), u1 = gelu_f(acc[0].y);
                const float u2 = gelu_f(acc[1].x), u3 = gelu_f(acc[1].y);
                s1 += (u0 + u1) + (u2 + u3);
                s2 = fmaf(u0, u0, fmaf(u1, u1, fmaf(u2, u2, fmaf(u3, u3, s2))));
                dst[q * NC + j] = pack4(u0, u1, u2, u3);
            }
            atomicAdd(&ssum[rep * NC + j], s1);
            atomicAdd(&ssq[rep * NC + j],  s2);
        }
    }
}

template<int K, bool FINAL>
__global__ __launch_bounds__(THREADS, 8)
void kbn(const unsigned long long* __restrict__ inr,
         const int* __restrict__ idx, const float* __restrict__ W, const float* __restrict__ bias,
         const float* __restrict__ gamma, const float* __restrict__ beta,
         const float* __restrict__ psum, const float* __restrict__ psq,
         unsigned long long* __restrict__ outr, float* __restrict__ fout,
         float* __restrict__ ssum, float* __restrict__ ssq)
{
    __shared__ unsigned long long tile[4 * NC];
    __shared__ float s_sc[NC], s_sh[NC];
    const int tid  = threadIdx.x;
    const int row0 = blockIdx.x * TRB;

    {
        const float4* src = (const float4*)(inr + (size_t)blockIdx.x * 4 * NC);
        float4*       dstl = (float4*)tile;
        for (int i = tid; i < 4 * NC / 2; i += THREADS) stage16(src + i, dstl + i);
    }
    for (int j = tid; j < NC; j += THREADS) {
        float s1 = 0.0f, s2 = 0.0f;
        #pragma unroll
        for (int r = 0; r < NREP; ++r) { s1 += psum[r * NC + j]; s2 += psq[r * NC + j]; }
        const float m   = s1 * INV_B;
        const float var = fmaf(-m, m, s2 * INV_B);
        const float sc  = gamma[j] * rsqrtf(var + EPS);
        s_sc[j] = sc;
        s_sh[j] = fmaf(-m, sc, beta[j]);
    }
    __syncthreads();

    const int rep = blockIdx.x & (NREP - 1);
    unsigned long long* dst = FINAL ? nullptr : (outr + (size_t)blockIdx.x * 4 * NC);
    #pragma unroll
    for (int slot = 0; slot < NSLOT; ++slot) {
        const int j = tid + slot * THREADS;
        if (j < NC) {
            int ji[K]; float jw[K];
            float jb = bias[j];
            #pragma unroll
            for (int k = 0; k < K; ++k) {
                const int   c = idx[K * j + k];
                const float w = W[K * j + k];
                ji[k] = c; jw[k] = w * s_sc[c]; jb = fmaf(w, s_sh[c], jb);
            }
            float s1 = 0.0f, s2 = 0.0f;
            #pragma unroll
            for (int q = 0; q < 4; ++q) {
                v2f acc[2] = { { jb, jb }, { jb, jb } };
                #pragma unroll
                for (int k = 0; k < K; ++k) fmaq(tile[q * NC + ji[k]], jw[k], acc);
                if (FINAL) {
                    fout[(size_t)(row0 + 4 * q + 0) * NC + j] = fmaxf(acc[0].x, 0.0f);
                    fout[(size_t)(row0 + 4 * q + 1) * NC + j] = fmaxf(acc[0].y, 0.0f);
                    fout[(size_t)(row0 + 4 * q + 2) * NC + j] = fmaxf(acc[1].x, 0.0f);
                    fout[(size_t)(row0 + 4 * q + 3) * NC + j] = fmaxf(acc[1].y, 0.0f);
                } else {
                    const float u0 = gelu_f(acc[0].x), u1 = gelu_f(acc[0].y);
                    const float u2 = gelu_f(acc[1].x), u3 = gelu_f(acc[1].y);
                    s1 += (u0 + u1) + (u2 + u3);
                    s2 = fmaf(u0, u0, fmaf(u1, u1, fmaf(u2, u2, fmaf(u3, u3, s2))));
                    dst[q * NC + j] = pack4(u0, u1, u2, u3);
                }
            }
            if (!FINAL) {
                atomicAdd(&ssum[rep * NC + j], s1);
                atomicAdd(&ssq[rep * NC + j],  s2);
            }
        }
    }
}

extern "C" void kernel_launch(void* const* d_in, const int* in_sizes, int n_in,
                              void* d_out, int out_size, void* d_ws, size_t ws_size,
                              hipStream_t stream)
{
    const float* x    = (const float*)d_in[0];
    const int*   idx1 = (const int*)  d_in[1];
    const float* W1   = (const float*)d_in[2];
    const float* b1   = (const float*)d_in[3];
    const int*   idx2 = (const int*)  d_in[4];
    const float* W2   = (const float*)d_in[5];
    const float* b2   = (const float*)d_in[6];
    const int*   idx3 = (const int*)  d_in[7];
    const float* W3   = (const float*)d_in[8];
    const float* b3   = (const float*)d_in[9];
    const float* g2   = (const float*)d_in[10];
    const float* be2  = (const float*)d_in[11];
    const float* g3   = (const float*)d_in[12];
    const float* be3  = (const float*)d_in[13];
    float* out = (float*)d_out;

    const size_t QN = (size_t)NBLK * 4 * NC;       // u64 elems per intermediate
    unsigned long long* r0 = (unsigned long long*)d_ws;
    unsigned long long* r1 = r0 + QN;
    float* p = (float*)(r1 + QN);
    float* sum2a = p; p += NREP * NC;  float* ssq2a = p; p += NREP * NC;
    float* sum3  = p; p += NREP * NC;  float* ssq3  = p; p += NREP * NC;
    float* sum2b = p; p += NREP * NC;  float* ssq2b = p; p += NREP * NC;

    hipMemsetAsync(sum2a, 0, 6 * NREP * NC * sizeof(float), stream);

    // ---- preferred path: single persistent cooperative kernel ----
    void* args[] = {
        (void*)&x,
        (void*)&idx1, (void*)&W1, (void*)&b1,
        (void*)&idx2, (void*)&W2, (void*)&b2,
        (void*)&idx3, (void*)&W3, (void*)&b3,
        (void*)&g2, (void*)&be2, (void*)&g3, (void*)&be3,
        (void*)&out,
        (void*)&sum2a, (void*)&ssq2a,
        (void*)&sum3,  (void*)&ssq3,
        (void*)&sum2b, (void*)&ssq2b
    };
    const hipError_t err = hipLaunchCooperativeKernel(
        (const void*)fused, dim3(NBLK), dim3(THREADS), args, 0, stream);
    if (err == hipSuccess) return;

    // ---- fallback: proven 4-kernel pipeline ----
    const dim3 grid(NBLK), blk(THREADS);
    k12<<<grid, blk, 0, stream>>>(x, idx1, W1, b1, idx2, W2, b2, r0, sum2a, ssq2a);
    kbn<8, false><<<grid, blk, 0, stream>>>(
        r0, idx3, W3, b3, g2, be2, sum2a, ssq2a, r1, nullptr, sum3, ssq3);
    kbn<4, false><<<grid, blk, 0, stream>>>(
        r1, idx2, W2, b2, g3, be3, sum3, ssq3, r0, nullptr, sum2b, ssq2b);
    kbn<2, true><<<grid, blk, 0, stream>>>(
        r0, idx1, W1, b1, g2, be2, sum2b, ssq2b, nullptr, out, nullptr, nullptr);
}

// Round 3
// 194.386 us; speedup vs baseline: 3.3299x; 3.3299x over previous
//
#include <hip/hip_runtime.h>
#include <math.h>

static constexpr int BROWS   = 16384;
static constexpr int NC      = 784;
static constexpr int THREADS = 512;
static constexpr int TRB     = 16;              // rows per tile/block
static constexpr int NBLK    = BROWS / TRB;     // 1024 blocks
static constexpr int NSLOT   = 2;               // ceil(784/512) column slots per thread
static constexpr float EPS   = 1e-5f;
static constexpr float INV_B = 1.0f / (float)BROWS;

// kred geometry: 49 blocks x 512 thr; 16 cols/block, 32 row-groups x 32 rows.
static constexpr int KRED_BLK  = 49;
static constexpr int KRED_COLS = 16;

#if defined(__has_builtin)
#if __has_builtin(__builtin_amdgcn_global_load_lds)
#define HAVE_ASYNC_LDS 1
#endif
#if __has_builtin(__builtin_amdgcn_rcpf)
#define HAVE_RCPF 1
#endif
#if __has_builtin(__builtin_elementwise_fma)
#define HAVE_EW_FMA 1
#endif
#endif

typedef float v2f __attribute__((ext_vector_type(2)));

__device__ __forceinline__ void stage16(const float4* g, float4* l) {
#ifdef HAVE_ASYNC_LDS
    __builtin_amdgcn_global_load_lds(
        (const __attribute__((address_space(1))) void*)g,
        (__attribute__((address_space(3))) void*)l, 16, 0, 0);
#else
    *l = *g;
#endif
}

// ---- bf16 helpers (raw u16 storage; RNE convert) ----
__device__ __forceinline__ unsigned short f2b(float f) {
    union { float f; unsigned u; } v; v.f = f;
    const unsigned r = v.u + 0x7fffu + ((v.u >> 16) & 1u);
    return (unsigned short)(r >> 16);
}
__device__ __forceinline__ unsigned pack2(float lo, float hi) {
    return (unsigned)f2b(lo) | ((unsigned)f2b(hi) << 16);
}
__device__ __forceinline__ unsigned long long pack4(float a, float b, float c, float d) {
    return (unsigned long long)pack2(a, b) | ((unsigned long long)pack2(c, d) << 32);
}
__device__ __forceinline__ float fast_rcp(float x) {
#ifdef HAVE_RCPF
    return __builtin_amdgcn_rcpf(x);
#else
    return 1.0f / x;
#endif
}

// tanh-form gelu (max |err| ~3e-4), branchless, correct limits.
__device__ __forceinline__ float gelu_f(float x) {
    const float u  = x * x;
    const float z  = x * fmaf(0.0356774081f, u, 0.7978845608f);
    const float e  = __expf(2.0f * z);
    const float r  = fast_rcp(e + 1.0f);
    const float t  = fmaf(-2.0f, r, 1.0f);
    const float hx = 0.5f * x;
    return fmaf(hx, t, hx);
}

// u64 = 4 bf16 rows of one column. Unpack to 2x v2f and packed-FMA.
__device__ __forceinline__ void fmaq(const unsigned long long v, const float w, v2f acc[2]) {
    const unsigned lo = (unsigned)v, hi = (unsigned)(v >> 32);
    union { unsigned u; float f; } a0, a1, b0, b1;
    a0.u = lo << 16; a1.u = lo & 0xffff0000u;
    b0.u = hi << 16; b1.u = hi & 0xffff0000u;
    const v2f a = { a0.f, a1.f }, b = { b0.f, b1.f };
    const v2f w2 = { w, w };
#ifdef HAVE_EW_FMA
    acc[0] = __builtin_elementwise_fma(a, w2, acc[0]);
    acc[1] = __builtin_elementwise_fma(b, w2, acc[1]);
#else
    acc[0] += a * w2;
    acc[1] += b * w2;
#endif
}

// ---------------- K_A: fused L1 -> gelu -> L2 -> gelu (+ bn2a partials) ----------------
// x staged to quad-u64 bf16 tileX; L1 reads tileX / writes tileH; L2 gathers tileH,
// stores quad region + per-block float2{sum,ssq} partials (NO atomics).
__global__ __launch_bounds__(THREADS, 6)
void k12(const float* __restrict__ x,
         const int* __restrict__ idx1, const float* __restrict__ W1, const float* __restrict__ b1,
         const int* __restrict__ idx2, const float* __restrict__ W2, const float* __restrict__ b2,
         unsigned long long* __restrict__ outr,
         float2* __restrict__ P)
{
    __shared__ unsigned long long tileX[4 * NC];   // 25088 B
    __shared__ unsigned long long tileH[4 * NC];   // 25088 B
    const int tid  = threadIdx.x;
    const int row0 = blockIdx.x * TRB;

    // stage x (fp32 row-major) -> quad bf16 tileX (coalesced dword reads per row)
    #pragma unroll
    for (int slot = 0; slot < NSLOT; ++slot) {
        const int c = tid + slot * THREADS;
        if (c < NC) {
            #pragma unroll
            for (int q = 0; q < 4; ++q) {
                const size_t base = (size_t)(row0 + 4 * q) * NC + c;
                tileX[q * NC + c] = pack4(x[base], x[base + NC], x[base + 2 * NC], x[base + 3 * NC]);
            }
        }
    }
    __syncthreads();

    // L1 (K=2): tileX -> tileH
    #pragma unroll
    for (int slot = 0; slot < NSLOT; ++slot) {
        const int j = tid + slot * THREADS;
        if (j < NC) {
            const int   c0 = idx1[2 * j], c1 = idx1[2 * j + 1];
            const float w0 = W1[2 * j],   w1 = W1[2 * j + 1], bb = b1[j];
            #pragma unroll
            for (int q = 0; q < 4; ++q) {
                v2f acc[2] = { { bb, bb }, { bb, bb } };
                fmaq(tileX[q * NC + c0], w0, acc);
                fmaq(tileX[q * NC + c1], w1, acc);
                tileH[q * NC + j] = pack4(gelu_f(acc[0].x), gelu_f(acc[0].y),
                                          gelu_f(acc[1].x), gelu_f(acc[1].y));
            }
        }
    }
    __syncthreads();

    // L2 (K=4) + gelu + partials + quad global store
    unsigned long long* dst = outr + (size_t)blockIdx.x * 4 * NC;
    float2* prow = P + (size_t)blockIdx.x * NC;
    #pragma unroll
    for (int slot = 0; slot < NSLOT; ++slot) {
        const int j = tid + slot * THREADS;
        if (j < NC) {
            int ji[4]; float jw[4];
            #pragma unroll
            for (int k = 0; k < 4; ++k) { ji[k] = idx2[4 * j + k]; jw[k] = W2[4 * j + k]; }
            const float jb = b2[j];
            float s1 = 0.0f, s2 = 0.0f;
            #pragma unroll
            for (int q = 0; q < 4; ++q) {
                v2f acc[2] = { { jb, jb }, { jb, jb } };
                #pragma unroll
                for (int k = 0; k < 4; ++k) fmaq(tileH[q * NC + ji[k]], jw[k], acc);
                const float u0 = gelu_f(acc[0].x), u1 = gelu_f(acc[0].y);
                const float u2 = gelu_f(acc[1].x), u3 = gelu_f(acc[1].y);
                s1 += (u0 + u1) + (u2 + u3);
                s2 = fmaf(u0, u0, fmaf(u1, u1, fmaf(u2, u2, fmaf(u3, u3, s2))));
                dst[q * NC + j] = pack4(u0, u1, u2, u3);
            }
            prow[j] = make_float2(s1, s2);    // coalesced 8B store, no RMW
        }
    }
}

// ---------------- kred: collapse P[1024][784] -> scsh[784] = {scale, shift} ----------------
// 49 blocks x 512 thr: 16 cols/block, 32 row-groups of 32 rows. Wave reads are
// 128B-aligned contiguous segments (row stride 6272B = 49*128).
__global__ __launch_bounds__(THREADS, 8)
void kred(const float2* __restrict__ P,
          const float* __restrict__ gamma, const float* __restrict__ beta,
          float2* __restrict__ scsh)
{
    __shared__ float redx[THREADS], redy[THREADS];
    const int tid = threadIdx.x;
    const int c0  = blockIdx.x * KRED_COLS;
    const int c   = tid & (KRED_COLS - 1);
    const int g   = tid >> 4;                     // 32 groups
    float s1 = 0.f, s2 = 0.f;
    const float2* base = P + (size_t)(g * 32) * NC + (c0 + c);
    #pragma unroll 8
    for (int r = 0; r < 32; ++r) {
        const float2 v = base[(size_t)r * NC];
        s1 += v.x; s2 += v.y;
    }
    redx[tid] = s1; redy[tid] = s2;
    __syncthreads();
    #pragma unroll
    for (int off = THREADS / 2; off >= KRED_COLS; off >>= 1) {
        if (tid < off) { redx[tid] += redx[tid + off]; redy[tid] += redy[tid + off]; }
        __syncthreads();
    }
    if (tid < KRED_COLS) {
        const int j = c0 + tid;
        const float m   = redx[tid] * INV_B;
        const float var = fmaf(-m, m, redy[tid] * INV_B);
        const float sc  = gamma[j] * rsqrtf(var + EPS);
        scsh[j] = make_float2(sc, fmaf(-m, sc, beta[j]));
    }
}

// -------- K_B/C/D: load precomputed scale/shift -> fold -> sparse -> act (+ partials) --------
template<int K, bool FINAL>
__global__ __launch_bounds__(THREADS, 8)
void kbn(const unsigned long long* __restrict__ inr,
         const int* __restrict__ idx, const float* __restrict__ W, const float* __restrict__ bias,
         const float2* __restrict__ scsh,
         unsigned long long* __restrict__ outr, float* __restrict__ fout,
         float2* __restrict__ P)
{
    __shared__ unsigned long long tile[4 * NC];    // 25088 B
    __shared__ float2 s_f[NC];                     //  6272 B
    const int tid  = threadIdx.x;
    const int row0 = blockIdx.x * TRB;

    {   // async DMA of the contiguous quad region (lane-linear dst)
        const float4* src = (const float4*)(inr + (size_t)blockIdx.x * 4 * NC);
        float4*       dstl = (float4*)tile;
        for (int i = tid; i < 4 * NC / 2; i += THREADS) stage16(src + i, dstl + i);
    }
    // stage precomputed scale/shift (6.3 KB, L2-hot; overlaps the DMA)
    for (int j = tid; j < NC; j += THREADS) s_f[j] = scsh[j];
    __syncthreads();   // drains DMA + publishes s_f

    unsigned long long* dst = FINAL ? nullptr : (outr + (size_t)blockIdx.x * 4 * NC);
    float2* prow = FINAL ? nullptr : (P + (size_t)blockIdx.x * NC);
    #pragma unroll
    for (int slot = 0; slot < NSLOT; ++slot) {
        const int j = tid + slot * THREADS;
        if (j < NC) {
            int ji[K]; float jw[K];
            float jb = bias[j];
            #pragma unroll
            for (int k = 0; k < K; ++k) {
                const int    c = idx[K * j + k];
                const float  w = W[K * j + k];
                const float2 f = s_f[c];
                ji[k] = c; jw[k] = w * f.x; jb = fmaf(w, f.y, jb);
            }
            float s1 = 0.0f, s2 = 0.0f;
            #pragma unroll
            for (int q = 0; q < 4; ++q) {
                v2f acc[2] = { { jb, jb }, { jb, jb } };
                #pragma unroll
                for (int k = 0; k < K; ++k) fmaq(tile[q * NC + ji[k]], jw[k], acc);
                if (FINAL) {
                    fout[(size_t)(row0 + 4 * q + 0) * NC + j] = fmaxf(acc[0].x, 0.0f);
                    fout[(size_t)(row0 + 4 * q + 1) * NC + j] = fmaxf(acc[0].y, 0.0f);
                    fout[(size_t)(row0 + 4 * q + 2) * NC + j] = fmaxf(acc[1].x, 0.0f);
                    fout[(size_t)(row0 + 4 * q + 3) * NC + j] = fmaxf(acc[1].y, 0.0f);
                } else {
                    const float u0 = gelu_f(acc[0].x), u1 = gelu_f(acc[0].y);
                    const float u2 = gelu_f(acc[1].x), u3 = gelu_f(acc[1].y);
                    s1 += (u0 + u1) + (u2 + u3);
                    s2 = fmaf(u0, u0, fmaf(u1, u1, fmaf(u2, u2, fmaf(u3, u3, s2))));
                    dst[q * NC + j] = pack4(u0, u1, u2, u3);
                }
            }
            if (!FINAL) prow[j] = make_float2(s1, s2);
        }
    }
}

extern "C" void kernel_launch(void* const* d_in, const int* in_sizes, int n_in,
                              void* d_out, int out_size, void* d_ws, size_t ws_size,
                              hipStream_t stream)
{
    const float* x    = (const float*)d_in[0];
    const int*   idx1 = (const int*)  d_in[1];
    const float* W1   = (const float*)d_in[2];
    const float* b1   = (const float*)d_in[3];
    const int*   idx2 = (const int*)  d_in[4];
    const float* W2   = (const float*)d_in[5];
    const float* b2   = (const float*)d_in[6];
    const int*   idx3 = (const int*)  d_in[7];
    const float* W3   = (const float*)d_in[8];
    const float* b3   = (const float*)d_in[9];
    const float* g2   = (const float*)d_in[10];
    const float* be2  = (const float*)d_in[11];
    const float* g3   = (const float*)d_in[12];
    const float* be3  = (const float*)d_in[13];
    float* out = (float*)d_out;

    const size_t QN = (size_t)NBLK * 4 * NC;       // u64 elems per intermediate
    // Quad-layout bf16 ping-pong + partials + precomputed scale/shift:
    //   k12      : r x  -> w r0, P        (bn2a partials)
    //   kredA    : r P  -> w scshA
    //   kbn<8>   : r r0, scshA -> w r1, P (bn3 partials)
    //   kredB    : r P  -> w scshB
    //   kbn<4>   : r r1, scshB -> w r0, P (bn2b partials)
    //   kredC    : r P  -> w scshC
    //   kbn<2,F> : r r0, scshC -> w out (fp32 row-major)
    unsigned long long* r0 = (unsigned long long*)d_ws;
    unsigned long long* r1 = r0 + QN;
    float2* P     = (float2*)(r1 + QN);            // 1024*784*8B = 6.4 MB
    float2* scshA = P + (size_t)NBLK * NC;
    float2* scshB = scshA + NC;
    float2* scshC = scshB + NC;

    const dim3 grid(NBLK), blk(THREADS);
    const dim3 rgrid(KRED_BLK);

    k12<<<grid, blk, 0, stream>>>(x, idx1, W1, b1, idx2, W2, b2, r0, P);
    kred<<<rgrid, blk, 0, stream>>>(P, g2, be2, scshA);
    kbn<8, false><<<grid, blk, 0, stream>>>(r0, idx3, W3, b3, scshA, r1, nullptr, P);
    kred<<<rgrid, blk, 0, stream>>>(P, g3, be3, scshB);
    kbn<4, false><<<grid, blk, 0, stream>>>(r1, idx2, W2, b2, scshB, r0, nullptr, P);
    kred<<<rgrid, blk, 0, stream>>>(P, g2, be2, scshC);
    kbn<2, true><<<grid, blk, 0, stream>>>(r0, idx1, W1, b1, scshC, nullptr, out, nullptr);
}

// Round 6
// 187.130 us; speedup vs baseline: 3.4590x; 1.0388x over previous
//
#include <hip/hip_runtime.h>
#include <math.h>

static constexpr int BROWS   = 16384;
static constexpr int NC      = 784;
static constexpr int TRB     = 16;              // rows per tile/block
static constexpr int THREADS = 512;
static constexpr int NBLK    = BROWS / TRB;     // 1024 blocks
static constexpr int NSLOT   = 2;               // ceil(784/512) column slots per thread
static constexpr int NREP    = 4;               // replicated stat accumulators
static constexpr float EPS   = 1e-5f;
static constexpr float INV_B = 1.0f / (float)BROWS;

#if defined(__has_builtin)
#if __has_builtin(__builtin_amdgcn_global_load_lds)
#define HAVE_ASYNC_LDS 1
#endif
#if __has_builtin(__builtin_amdgcn_rcpf)
#define HAVE_RCPF 1
#endif
#if __has_builtin(__builtin_elementwise_fma)
#define HAVE_EW_FMA 1
#endif
#endif

typedef float v2f __attribute__((ext_vector_type(2)));

__device__ __forceinline__ void stage16(const float4* g, float4* l) {
#ifdef HAVE_ASYNC_LDS
    __builtin_amdgcn_global_load_lds(
        (const __attribute__((address_space(1))) void*)g,
        (__attribute__((address_space(3))) void*)l, 16, 0, 0);
#else
    *l = *g;
#endif
}

// ---- bf16 helpers (raw u16 storage; RNE convert) ----
__device__ __forceinline__ unsigned short f2b(float f) {
    union { float f; unsigned u; } v; v.f = f;
    const unsigned r = v.u + 0x7fffu + ((v.u >> 16) & 1u);
    return (unsigned short)(r >> 16);
}
__device__ __forceinline__ unsigned pack2(float lo, float hi) {
    return (unsigned)f2b(lo) | ((unsigned)f2b(hi) << 16);
}
__device__ __forceinline__ unsigned long long pack4(float a, float b, float c, float d) {
    return (unsigned long long)pack2(a, b) | ((unsigned long long)pack2(c, d) << 32);
}
__device__ __forceinline__ float fast_rcp(float x) {
#ifdef HAVE_RCPF
    return __builtin_amdgcn_rcpf(x);
#else
    return 1.0f / x;
#endif
}

// tanh-form gelu (max |err| ~3e-4, far under the 0.2625 budget), branchless.
__device__ __forceinline__ float gelu_f(float x) {
    const float u  = x * x;
    const float z  = x * fmaf(0.0356774081f, u, 0.7978845608f);
    const float e  = __expf(2.0f * z);            // e^{2z}
    const float r  = fast_rcp(e + 1.0f);
    const float t  = fmaf(-2.0f, r, 1.0f);        // tanh(z)
    const float hx = 0.5f * x;
    return fmaf(hx, t, hx);
}

// u64 = 4 bf16 rows of one column (rows 4q..4q+3). Unpack to 2x v2f and FMA
// with packed v_pk_fma_f32.
__device__ __forceinline__ void fmaq(const unsigned long long v, const float w, v2f acc[2]) {
    const unsigned lo = (unsigned)v, hi = (unsigned)(v >> 32);
    union { unsigned u; float f; } a0, a1, b0, b1;
    a0.u = lo << 16; a1.u = lo & 0xffff0000u;
    b0.u = hi << 16; b1.u = hi & 0xffff0000u;
    const v2f a = { a0.f, a1.f }, b = { b0.f, b1.f };
    const v2f w2 = { w, w };
#ifdef HAVE_EW_FMA
    acc[0] = __builtin_elementwise_fma(a, w2, acc[0]);
    acc[1] = __builtin_elementwise_fma(b, w2, acc[1]);
#else
    acc[0] += a * w2;
    acc[1] += b * w2;
#endif
}

// Batch-gather: issue ALL CH*4 ds_read_b64 into registers first, THEN the FMA
// block. One lgkmcnt wait per chunk instead of per-read dependency stalls.
// CH<=4 keeps the in-flight data at <=32 VGPRs (fits launch_bounds(512,6)).
template<int CH>
__device__ __forceinline__ void gchunk(const unsigned long long* __restrict__ tile,
                                       const int* ji, const float* jw,
                                       v2f acc[4][2])
{
    unsigned long long t[CH][4];
    #pragma unroll
    for (int k = 0; k < CH; ++k) {
        #pragma unroll
        for (int q = 0; q < 4; ++q) t[k][q] = tile[q * NC + ji[k]];
    }
    #pragma unroll
    for (int k = 0; k < CH; ++k) {
        #pragma unroll
        for (int q = 0; q < 4; ++q) fmaq(t[k][q], jw[k], acc[q]);
    }
}

template<int K>
__device__ __forceinline__ void gacc(const unsigned long long* __restrict__ tile,
                                     const int* ji, const float* jw, const float jb,
                                     v2f acc[4][2])
{
    #pragma unroll
    for (int q = 0; q < 4; ++q) { acc[q][0] = (v2f){ jb, jb }; acc[q][1] = (v2f){ jb, jb }; }
    if (K == 8) {
        gchunk<4>(tile, ji,     jw,     acc);
        gchunk<4>(tile, ji + 4, jw + 4, acc);
    } else {
        gchunk<K>(tile, ji, jw, acc);
    }
}

// ---------------- K_A: fused L1 -> gelu -> L2 -> gelu (+ bn2a stats) ----------------
__global__ __launch_bounds__(THREADS, 6)
void k12(const float* __restrict__ x,
         const int* __restrict__ idx1, const float* __restrict__ W1, const float* __restrict__ b1,
         const int* __restrict__ idx2, const float* __restrict__ W2, const float* __restrict__ b2,
         unsigned long long* __restrict__ outr,
         float* __restrict__ ssum, float* __restrict__ ssq)
{
    __shared__ unsigned long long tileX[4 * NC];   // 25088 B
    __shared__ unsigned long long tileH[4 * NC];   // 25088 B
    const int tid  = threadIdx.x;
    const int row0 = blockIdx.x * TRB;

    // stage x (fp32 row-major) -> quad bf16 tileX (coalesced dword reads per row)
    #pragma unroll
    for (int slot = 0; slot < NSLOT; ++slot) {
        const int c = tid + slot * THREADS;
        if (c < NC) {
            #pragma unroll
            for (int q = 0; q < 4; ++q) {
                const size_t base = (size_t)(row0 + 4 * q) * NC + c;
                tileX[q * NC + c] = pack4(x[base], x[base + NC], x[base + 2 * NC], x[base + 3 * NC]);
            }
        }
    }
    __syncthreads();

    // L1 (K=2): tileX -> tileH (batched loads for ILP)
    #pragma unroll
    for (int slot = 0; slot < NSLOT; ++slot) {
        const int j = tid + slot * THREADS;
        if (j < NC) {
            int ji[2]; float jw[2];
            ji[0] = idx1[2 * j]; ji[1] = idx1[2 * j + 1];
            jw[0] = W1[2 * j];   jw[1] = W1[2 * j + 1];
            v2f acc[4][2];
            gacc<2>(tileX, ji, jw, b1[j], acc);
            #pragma unroll
            for (int q = 0; q < 4; ++q) {
                tileH[q * NC + j] = pack4(gelu_f(acc[q][0].x), gelu_f(acc[q][0].y),
                                          gelu_f(acc[q][1].x), gelu_f(acc[q][1].y));
            }
        }
    }
    __syncthreads();

    // L2 (K=4) + gelu + stats + quad global store
    const int rep = blockIdx.x & (NREP - 1);
    unsigned long long* dst = outr + (size_t)blockIdx.x * 4 * NC;
    #pragma unroll
    for (int slot = 0; slot < NSLOT; ++slot) {
        const int j = tid + slot * THREADS;
        if (j < NC) {
            int ji[4]; float jw[4];
            #pragma unroll
            for (int k = 0; k < 4; ++k) { ji[k] = idx2[4 * j + k]; jw[k] = W2[4 * j + k]; }
            v2f acc[4][2];
            gacc<4>(tileH, ji, jw, b2[j], acc);
            float s1 = 0.0f, s2 = 0.0f;
            #pragma unroll
            for (int q = 0; q < 4; ++q) {
                const float u0 = gelu_f(acc[q][0].x), u1 = gelu_f(acc[q][0].y);
                const float u2 = gelu_f(acc[q][1].x), u3 = gelu_f(acc[q][1].y);
                s1 += (u0 + u1) + (u2 + u3);
                s2 = fmaf(u0, u0, fmaf(u1, u1, fmaf(u2, u2, fmaf(u3, u3, s2))));
                dst[q * NC + j] = pack4(u0, u1, u2, u3);
            }
            atomicAdd(&ssum[rep * NC + j], s1);
            atomicAdd(&ssq[rep * NC + j],  s2);
        }
    }
}

// -------- K_B/C/D: fold prev BN into weights -> sparse -> act (+ stats) --------
template<int K, bool FINAL>
__global__ __launch_bounds__(THREADS, 6)    // was 8: <=64 VGPR strangled gather ILP
void kbn(const unsigned long long* __restrict__ inr,
         const int* __restrict__ idx, const float* __restrict__ W, const float* __restrict__ bias,
         const float* __restrict__ gamma, const float* __restrict__ beta,
         const float* __restrict__ psum, const float* __restrict__ psq,
         unsigned long long* __restrict__ outr, float* __restrict__ fout,
         float* __restrict__ ssum, float* __restrict__ ssq)
{
    __shared__ unsigned long long tile[4 * NC];    // 25088 B
    __shared__ float s_sc[NC], s_sh[NC];           //  6272 B
    const int tid  = threadIdx.x;
    const int row0 = blockIdx.x * TRB;

    {   // async DMA of the contiguous quad region (lane-linear dst)
        const float4* src = (const float4*)(inr + (size_t)blockIdx.x * 4 * NC);
        float4*       dstl = (float4*)tile;
        for (int i = tid; i < 4 * NC / 2; i += THREADS) stage16(src + i, dstl + i);
    }
    // finalize previous BN into scale/shift (L2-hot; overlaps the DMA)
    for (int j = tid; j < NC; j += THREADS) {
        float s1 = 0.0f, s2 = 0.0f;
        #pragma unroll
        for (int r = 0; r < NREP; ++r) { s1 += psum[r * NC + j]; s2 += psq[r * NC + j]; }
        const float m   = s1 * INV_B;
        const float var = fmaf(-m, m, s2 * INV_B);
        const float sc  = gamma[j] * rsqrtf(var + EPS);
        s_sc[j] = sc;
        s_sh[j] = fmaf(-m, sc, beta[j]);
    }
    __syncthreads();   // drains DMA + publishes sc/sh

    const int rep = blockIdx.x & (NREP - 1);
    unsigned long long* dst = FINAL ? nullptr : (outr + (size_t)blockIdx.x * 4 * NC);
    #pragma unroll
    for (int slot = 0; slot < NSLOT; ++slot) {
        const int j = tid + slot * THREADS;
        if (j < NC) {
            int ji[K]; float jw[K];
            float jb = bias[j];
            #pragma unroll
            for (int k = 0; k < K; ++k) {
                const int   c = idx[K * j + k];
                const float w = W[K * j + k];
                ji[k] = c; jw[k] = w * s_sc[c]; jb = fmaf(w, s_sh[c], jb);
            }
            v2f acc[4][2];
            gacc<K>(tile, ji, jw, jb, acc);
            if (FINAL) {
                #pragma unroll
                for (int q = 0; q < 4; ++q) {
                    fout[(size_t)(row0 + 4 * q + 0) * NC + j] = fmaxf(acc[q][0].x, 0.0f);
                    fout[(size_t)(row0 + 4 * q + 1) * NC + j] = fmaxf(acc[q][0].y, 0.0f);
                    fout[(size_t)(row0 + 4 * q + 2) * NC + j] = fmaxf(acc[q][1].x, 0.0f);
                    fout[(size_t)(row0 + 4 * q + 3) * NC + j] = fmaxf(acc[q][1].y, 0.0f);
                }
            } else {
                float s1 = 0.0f, s2 = 0.0f;
                #pragma unroll
                for (int q = 0; q < 4; ++q) {
                    const float u0 = gelu_f(acc[q][0].x), u1 = gelu_f(acc[q][0].y);
                    const float u2 = gelu_f(acc[q][1].x), u3 = gelu_f(acc[q][1].y);
                    s1 += (u0 + u1) + (u2 + u3);
                    s2 = fmaf(u0, u0, fmaf(u1, u1, fmaf(u2, u2, fmaf(u3, u3, s2))));
                    dst[q * NC + j] = pack4(u0, u1, u2, u3);
                }
                atomicAdd(&ssum[rep * NC + j], s1);
                atomicAdd(&ssq[rep * NC + j],  s2);
            }
        }
    }
}

extern "C" void kernel_launch(void* const* d_in, const int* in_sizes, int n_in,
                              void* d_out, int out_size, void* d_ws, size_t ws_size,
                              hipStream_t stream)
{
    const float* x    = (const float*)d_in[0];
    const int*   idx1 = (const int*)  d_in[1];
    const float* W1   = (const float*)d_in[2];
    const float* b1   = (const float*)d_in[3];
    const int*   idx2 = (const int*)  d_in[4];
    const float* W2   = (const float*)d_in[5];
    const float* b2   = (const float*)d_in[6];
    const int*   idx3 = (const int*)  d_in[7];
    const float* W3   = (const float*)d_in[8];
    const float* b3   = (const float*)d_in[9];
    const float* g2   = (const float*)d_in[10];
    const float* be2  = (const float*)d_in[11];
    const float* g3   = (const float*)d_in[12];
    const float* be3  = (const float*)d_in[13];
    float* out = (float*)d_out;

    const size_t QN = (size_t)NBLK * 4 * NC;       // u64 elems per intermediate
    // Quad-layout bf16 ping-pong:
    //   k12      : r x  -> w r0
    //   kbn<8>   : r r0 -> w r1
    //   kbn<4>   : r r1 -> w r0
    //   kbn<2,F> : r r0 -> w out (fp32 row-major)
    unsigned long long* r0 = (unsigned long long*)d_ws;
    unsigned long long* r1 = r0 + QN;
    float* p = (float*)(r1 + QN);
    float* sum2a = p; p += NREP * NC;  float* ssq2a = p; p += NREP * NC;
    float* sum3  = p; p += NREP * NC;  float* ssq3  = p; p += NREP * NC;
    float* sum2b = p; p += NREP * NC;  float* ssq2b = p; p += NREP * NC;

    hipMemsetAsync(sum2a, 0, 6 * NREP * NC * sizeof(float), stream);

    const dim3 grid(NBLK), blk(THREADS);

    k12<<<grid, blk, 0, stream>>>(x, idx1, W1, b1, idx2, W2, b2, r0, sum2a, ssq2a);
    kbn<8, false><<<grid, blk, 0, stream>>>(
        r0, idx3, W3, b3, g2, be2, sum2a, ssq2a, r1, nullptr, sum3, ssq3);
    kbn<4, false><<<grid, blk, 0, stream>>>(
        r1, idx2, W2, b2, g3, be3, sum3, ssq3, r0, nullptr, sum2b, ssq2b);
    kbn<2, true><<<grid, blk, 0, stream>>>(
        r0, idx1, W1, b1, g2, be2, sum2b, ssq2b, nullptr, out, nullptr, nullptr);
}